// Round 1
// baseline (71.714 us; speedup 1.0000x reference)
//
#include <hip/hip_runtime.h>
#include <math.h>

#define N 10
#define C 4

__global__ void Model_78056735637556_kernel(const float* __restrict__ x,
                                            const float* __restrict__ c,
                                            const float* __restrict__ r,
                                            float* __restrict__ out) {
    if (threadIdx.x != 0 || blockIdx.x != 0) return;

    // boxes = outer(x, c); scores = r * x; max_coord = boxes.max()
    float boxes[N][C];
    float scores[N];
    float maxc = -INFINITY;
    for (int i = 0; i < N; ++i) {
        float xi = x[i];
        for (int k = 0; k < C; ++k) {
            float b = xi * c[k];
            boxes[i][k] = b;
            maxc = fmaxf(maxc, b);
        }
        scores[i] = r[i] * xi;
    }

    // order = argsort(-scores): stable descending sort (insertion sort,
    // strict compare keeps ties in original index order == jnp stable argsort)
    int order[N];
    for (int i = 0; i < N; ++i) order[i] = i;
    for (int i = 1; i < N; ++i) {
        int oi = order[i];
        float s = scores[oi];
        int j = i - 1;
        while (j >= 0 && scores[order[j]] < s) {
            order[j + 1] = order[j];
            --j;
        }
        order[j + 1] = oi;
    }

    // boxes_nms[order[i]] = boxes[order[i]] + order[i] * (max_coord + 1)
    // (offsets indexed by ORIGINAL row, gathered by order)
    float off = maxc + 1.0f;
    float bn[N][C];
    for (int i = 0; i < N; ++i) {
        int o = order[i];
        float d = (float)o * off;
        for (int k = 0; k < C; ++k) bn[i][k] = boxes[o][k] + d;
    }

    // area per sorted box (x1,y1,x2,y2 = cols 0,1,2,3)
    float area[N];
    for (int i = 0; i < N; ++i)
        area[i] = (bn[i][2] - bn[i][0]) * (bn[i][3] - bn[i][1]);

    // sequential NMS: for i ascending, if keep[i], suppress j>i with iou>thr.
    // Matches fori_loop body: sup = (iou[i] > 0) & keep[i] & (j > i).
    bool keep[N];
    for (int i = 0; i < N; ++i) keep[i] = true;
    for (int i = 0; i < N; ++i) {
        if (!keep[i]) continue;
        for (int j = i + 1; j < N; ++j) {
            float iw = fminf(bn[i][2], bn[j][2]) - fmaxf(bn[i][0], bn[j][0]);
            iw = fmaxf(iw, 0.0f);
            float ih = fminf(bn[i][3], bn[j][3]) - fmaxf(bn[i][1], bn[j][1]);
            ih = fmaxf(ih, 0.0f);
            float inter = iw * ih;
            float iou = inter / (area[i] + area[j] - inter);
            if (iou > 0.0f) keep[j] = false;  // NaN > 0 is false, same as JAX
        }
    }

    // out[i] = keep[i] ? boxes[order[i]] : 0
    for (int i = 0; i < N; ++i) {
        int o = order[i];
        for (int k = 0; k < C; ++k)
            out[i * C + k] = keep[i] ? boxes[o][k] : 0.0f;
    }
}

extern "C" void kernel_launch(void* const* d_in, const int* in_sizes, int n_in,
                              void* d_out, int out_size, void* d_ws, size_t ws_size,
                              hipStream_t stream) {
    const float* x = (const float*)d_in[0];
    const float* c = (const float*)d_in[1];
    const float* r = (const float*)d_in[2];
    float* out = (float*)d_out;
    Model_78056735637556_kernel<<<1, 64, 0, stream>>>(x, c, r, out);
}

// Round 2
// 62.269 us; speedup vs baseline: 1.1517x; 1.1517x over previous
//
#include <hip/hip_runtime.h>
#include <math.h>

#define N 10
#define C 4

__global__ __launch_bounds__(64, 1)
void Model_78056735637556_kernel(const float* __restrict__ x,
                                 const float* __restrict__ c,
                                 const float* __restrict__ r,
                                 float* __restrict__ out) {
    __shared__ float s_boxes[N][C];
    __shared__ float s_scores[N];
    __shared__ int   s_order[N];
    __shared__ int   s_keep[N];

    const int t = threadIdx.x;

    // Parallel producer: boxes = outer(x,c), scores = r*x
    if (t < N * C) {
        int i = t / C, k = t % C;
        s_boxes[i][k] = x[i] * c[k];
    }
    if (t < N) s_scores[t] = r[t] * x[t];
    __syncthreads();

    // Serial core on lane 0: max, stable argsort, NMS (O(100) ops — latency,
    // not throughput; one lane is optimal at this size)
    if (t == 0) {
        float maxc = -INFINITY;
        for (int i = 0; i < N; ++i)
            for (int k = 0; k < C; ++k) maxc = fmaxf(maxc, s_boxes[i][k]);

        // stable descending insertion sort (ties keep original index order,
        // matching jnp.argsort(-scores) stability)
        int order[N];
        for (int i = 0; i < N; ++i) order[i] = i;
        for (int i = 1; i < N; ++i) {
            int oi = order[i];
            float s = s_scores[oi];
            int j = i - 1;
            while (j >= 0 && s_scores[order[j]] < s) {
                order[j + 1] = order[j];
                --j;
            }
            order[j + 1] = oi;
        }

        // boxes_nms: offsets indexed by ORIGINAL row, gathered by order
        float off = maxc + 1.0f;
        float bn[N][C];
        float area[N];
        for (int i = 0; i < N; ++i) {
            int o = order[i];
            float d = (float)o * off;
            for (int k = 0; k < C; ++k) bn[i][k] = s_boxes[o][k] + d;
            area[i] = (bn[i][2] - bn[i][0]) * (bn[i][3] - bn[i][1]);
        }

        // sequential suppression: sup = (iou[i] > 0) & keep[i] & (j > i)
        int keep[N];
        for (int i = 0; i < N; ++i) keep[i] = 1;
        for (int i = 0; i < N; ++i) {
            if (!keep[i]) continue;
            for (int j = i + 1; j < N; ++j) {
                float iw = fmaxf(fminf(bn[i][2], bn[j][2]) - fmaxf(bn[i][0], bn[j][0]), 0.0f);
                float ih = fmaxf(fminf(bn[i][3], bn[j][3]) - fmaxf(bn[i][1], bn[j][1]), 0.0f);
                float inter = iw * ih;
                float iou = inter / (area[i] + area[j] - inter);
                if (iou > 0.0f) keep[j] = 0;  // NaN compares false, same as JAX
            }
        }
        for (int i = 0; i < N; ++i) { s_order[i] = order[i]; s_keep[i] = keep[i]; }
    }
    __syncthreads();

    // Parallel consumer: out[i] = keep[i] ? boxes[order[i]] : 0
    if (t < N * C) {
        int i = t / C, k = t % C;
        out[t] = s_keep[i] ? s_boxes[s_order[i]][k] : 0.0f;
    }
}

extern "C" void kernel_launch(void* const* d_in, const int* in_sizes, int n_in,
                              void* d_out, int out_size, void* d_ws, size_t ws_size,
                              hipStream_t stream) {
    const float* x = (const float*)d_in[0];
    const float* c = (const float*)d_in[1];
    const float* r = (const float*)d_in[2];
    float* out = (float*)d_out;
    Model_78056735637556_kernel<<<1, 64, 0, stream>>>(x, c, r, out);
}